// Round 1
// baseline (1082.146 us; speedup 1.0000x reference)
//
#include <hip/hip_runtime.h>
#include <hip/hip_bf16.h>

#define TT 200
#define NBATCH 256
#define HID 128
#define G4 512
#define VOC 50000

// Design rule learned R1-R3: the backend pins 1024-thr blocks to <=128 VGPRs and
// 512-thr blocks to 128 unless it feels like more. So every kernel below is
// designed to need <= ~110 VGPRs. Block-uniform data goes through SGPRs
// (readfirstlane-forced uniformity -> s_load), bulk reuse goes to LDS.

// ---------------- Kernel XW: XW = ET @ W + b  (50000 x 512) ----------------
// 1024 thr: kh=tid>>9 (K half, wave-uniform), j=tid&511. wcol[64] in VGPRs,
// ET row values via scalar loads (uniform). Halves combined through LDS.
__global__ __launch_bounds__(1024) void kxw(
    const float* __restrict__ ET,       // (V, H)
    const float* __restrict__ W,        // (H, 4H)
    const float* __restrict__ b,        // (4H)
    float* __restrict__ XW)             // (V, 4H)
{
    const int tid = threadIdx.x;
    const int kh = __builtin_amdgcn_readfirstlane(tid >> 9);  // 0/1, wave-uniform
    const int j = tid & 511;
    const int rbase0 = blockIdx.x * 128;

    __shared__ __align__(16) float pA[16][2][G4];   // 64 KB

    float wcol[64];
    #pragma unroll
    for (int kk = 0; kk < 64; ++kk) wcol[kk] = W[(size_t)(kh * 64 + kk) * G4 + j];
    const float bj = b[j];

    for (int batch = 0; batch < 8; ++batch) {
        const int rb = rbase0 + batch * 16;
        float acc[16];
        #pragma unroll
        for (int r = 0; r < 16; ++r) {
            int row = rb + r; row = row < VOC ? row : VOC - 1;   // uniform
            const float* e = ET + (size_t)row * HID + kh * 64;   // uniform -> s_load
            float a0 = 0.f, a1 = 0.f, a2 = 0.f, a3 = 0.f;
            #pragma unroll
            for (int q = 0; q < 16; ++q) {
                a0 = fmaf(e[4*q+0], wcol[4*q+0], a0);
                a1 = fmaf(e[4*q+1], wcol[4*q+1], a1);
                a2 = fmaf(e[4*q+2], wcol[4*q+2], a2);
                a3 = fmaf(e[4*q+3], wcol[4*q+3], a3);
            }
            acc[r] = (a0 + a1) + (a2 + a3);
        }
        #pragma unroll
        for (int r = 0; r < 16; ++r) pA[r][kh][j] = acc[r];
        __syncthreads();
        if (tid < G4) {
            for (int r = 0; r < 16; ++r) {
                const int row = rb + r;
                if (row < VOC)
                    XW[(size_t)row * G4 + tid] = pA[r][0][tid] + pA[r][1][tid] + bj;
            }
        }
        __syncthreads();
    }
}

// ---------------- Kernel 2: recurrence, one 1024-thr block per n ----------------
// h history in regs (hreg[25], group g=tid>>7 owns rows [25g,25g+25)),
// c history in LDS (c_lds[h][209], pad 209 -> conflict-free),
// U in regs (ucol[64], K-half kh=tid>>9).
// R4 change: software-pipelined staging (T14). seq/mask preloaded to LDS once;
// XW row + topo row for step t+1 prefetched into REGISTERS at the top of step t
// (threads 0-511 XW, 512-767 topo -> disjoint, parallel issue) and committed to
// the double-buffered LDS slots in the phase-B region (before barrier C).
// Kills the per-step serialized chain [s_load seq -> glb XW/topo -> ds_write ->
// barrier] and drops 4 barriers/step to 3.
__global__ __launch_bounds__(1024) void k2_recur(
    const float* __restrict__ topo,     // (T, N, T)
    const float* __restrict__ mask,     // (T, N)
    const float* __restrict__ U,        // (H, 4H)
    const int*   __restrict__ seq,      // (T, N)
    const float* __restrict__ XW,       // (V, 4H)
    float* __restrict__ hmT)            // (H, N) transposed h_mean
{
    const int n   = blockIdx.x;
    const int tid = threadIdx.x;
    const int g   = __builtin_amdgcn_readfirstlane(tid >> 7);   // 0..7
    const int h   = tid & 127;
    const int kh  = __builtin_amdgcn_readfirstlane(tid >> 9);   // 0..1
    const int j   = tid & 511;

    __shared__ float c_lds[HID][209];                 // 104.5 KB, c_lds[h][t']
    __shared__ __align__(16) float topoS[2][8][32];   // double-buffered topo row
    __shared__ float part_h[8][HID];
    __shared__ float part_c[8][HID];
    __shared__ __align__(16) float hsum[HID];
    __shared__ float csum[HID];
    __shared__ float pB[2][G4];
    __shared__ float xgl[2][G4];
    __shared__ int   seq_l[TT];
    __shared__ float mask_l[TT];

    float ucol[64];
    #pragma unroll
    for (int kk = 0; kk < 64; ++kk) ucol[kk] = U[(size_t)(kh * 64 + kk) * G4 + j];

    float hreg[25];
    #pragma unroll
    for (int k = 0; k < 25; ++k) hreg[k] = 0.f;
    for (int i = tid; i < HID * 209; i += 1024) (&c_lds[0][0])[i] = 0.f;

    // one-time preload: per-n sequence + mask rows (kills per-step s_load chain)
    if (tid < TT) {
        seq_l[tid]  = seq[tid * NBATCH + n];
        mask_l[tid] = mask[tid * NBATCH + n];
    }
    // prologue stage for t=0 (addresses straight from global, uniform)
    if (tid < G4) {
        xgl[0][tid] = XW[(size_t)seq[n] * G4 + tid];
    } else if (tid < 768) {
        const int tt = tid - 512;
        const int gg = tt >> 5, ii = tt & 31;
        topoS[0][gg][ii] = (ii < 25)
            ? topo[(size_t)n * TT + 25 * gg + ii] : 0.f;   // t=0 row
    }

    float hmacc = 0.f, len = 0.f;
    __syncthreads();

    for (int t = 0; t < TT; ++t) {
        const int cur = t & 1, nxt = cur ^ 1;

        // ---- issue prefetch for step t+1 (registers; committed before bar C) ----
        const int tn = (t + 1 < TT) ? t + 1 : t;
        float pf = 0.f;
        if (tid < G4) {
            pf = XW[(size_t)seq_l[tn] * G4 + tid];
        } else if (tid < 768) {
            const int tt = tid - 512;
            const int gg = tt >> 5, ii = tt & 31;
            pf = (ii < 25)
                ? topo[((size_t)tn * NBATCH + n) * TT + 25 * gg + ii] : 0.f;
        }
        const float m = mask_l[t];

        // ---- phase A: h partial from regs, c partial from LDS; rows >= t are zero ----
        float ah0 = 0.f, ah1 = 0.f, ac0 = 0.f, ac1 = 0.f;
        const int base = 25 * g;
        const float4* tp4 = (const float4*)&topoS[cur][g][0];
        const float* crow = &c_lds[h][0];
        #pragma unroll
        for (int kk = 0; kk < 6; ++kk) {
            if (base + 4 * kk < t) {        // perf guard only; data is 0 beyond t
                float4 tp = tp4[kk];
                ah0 = fmaf(tp.x, hreg[4*kk+0], ah0);
                ac0 = fmaf(tp.x, crow[base+4*kk+0], ac0);
                ah1 = fmaf(tp.y, hreg[4*kk+1], ah1);
                ac1 = fmaf(tp.y, crow[base+4*kk+1], ac1);
                ah0 = fmaf(tp.z, hreg[4*kk+2], ah0);
                ac0 = fmaf(tp.z, crow[base+4*kk+2], ac0);
                ah1 = fmaf(tp.w, hreg[4*kk+3], ah1);
                ac1 = fmaf(tp.w, crow[base+4*kk+3], ac1);
            }
        }
        if (base + 24 < t) {
            const float tpl = topoS[cur][g][24];
            ah0 = fmaf(tpl, hreg[24], ah0);
            ac0 = fmaf(tpl, crow[base+24], ac0);
        }
        part_h[g][h] = ah0 + ah1;
        part_c[g][h] = ac0 + ac1;
        __syncthreads();                                        // (A)

        if (tid < HID) {
            float s = 0.f;
            #pragma unroll
            for (int gg = 0; gg < 8; ++gg) s += part_h[gg][tid];
            hsum[tid] = s;
        } else if (tid < 2 * HID) {
            const int hh = tid - HID;
            float s = 0.f;
            #pragma unroll
            for (int gg = 0; gg < 8; ++gg) s += part_c[gg][hh];
            csum[hh] = s;
        }
        __syncthreads();                                        // (B)

        // ---- phase B: pB[kh][j] = hsum[kh-half] . U-half column ----
        {
            float a0 = 0.f, a1 = 0.f, a2 = 0.f, a3 = 0.f;
            const float4* hs4 = (const float4*)&hsum[kh * 64];
            #pragma unroll
            for (int q = 0; q < 16; ++q) {
                float4 x = hs4[q];
                a0 = fmaf(x.x, ucol[4*q+0], a0);
                a1 = fmaf(x.y, ucol[4*q+1], a1);
                a2 = fmaf(x.z, ucol[4*q+2], a2);
                a3 = fmaf(x.w, ucol[4*q+3], a3);
            }
            pB[kh][j] = (a0 + a1) + (a2 + a3);
        }
        // commit prefetch to the nxt buffers (separated from next phase A by bar C)
        if (tid < G4) {
            xgl[nxt][tid] = pf;
        } else if (tid < 768) {
            const int tt = tid - 512;
            topoS[nxt][tt >> 5][tt & 31] = pf;
        }
        __syncthreads();                                        // (C)

        // ---- cell: owning group g* = t/25 (wave-uniform branch) ----
        const int gstar = t / 25;
        if (g == gstar) {
            const float iv = pB[0][h]       + pB[1][h]       + xgl[cur][h];
            const float fv = pB[0][128+h]   + pB[1][128+h]   + xgl[cur][128+h];
            const float ov = pB[0][256+h]   + pB[1][256+h]   + xgl[cur][256+h];
            const float gv = pB[0][384+h]   + pB[1][384+h]   + xgl[cur][384+h];
            const float si = 1.f / (1.f + expf(-iv));
            const float sf = 1.f / (1.f + expf(-fv));
            const float so = 1.f / (1.f + expf(-ov));
            const float tg = tanhf(gv);
            const float cn = m * (sf * csum[h] + si * tg);
            const float hn = m * (so * tanhf(cn));
            const int kt = t - 25 * gstar;
            #pragma unroll
            for (int k = 0; k < 25; ++k) if (k == kt) hreg[k] = hn;
            c_lds[h][t] = cn;      // same thread re-reads it next steps: no barrier
            hmacc = fmaf(m, hn, hmacc);
        }
        len += m;
        // next phase A reads topoS[nxt] (written before bar C) and c_lds (same-
        // thread). part_/hsum/csum/pB rewrites are >=1 barrier from their readers.
    }

    part_h[g][h] = hmacc;     // unique slot per thread
    __syncthreads();
    if (tid < HID) {
        float s = 0.f;
        #pragma unroll
        for (int gg = 0; gg < 8; ++gg) s += part_h[gg][tid];
        hmT[(size_t)tid * NBATCH + n] = s / len;   // transposed for k3
    }
}

// ---------------- Kernel 3: out = h_mean @ W_out + b_out  (k-outer matvec) ----------------
// 512 thr: v = column; acc[32] rows; Wout coalesced, hmT row-slice via s_load.
__global__ __launch_bounds__(512) void k3_out(
    const float* __restrict__ hmT,     // (H, N)
    const float* __restrict__ Wout,    // (H, V)
    const float* __restrict__ bout,    // (V)
    float* __restrict__ out)           // (N, V)
{
    const int tid = threadIdx.x;
    const int v = blockIdx.x * 512 + tid;
    const int r0 = blockIdx.y * 32;
    const int vc = v < VOC ? v : VOC - 1;

    float acc[32];
    #pragma unroll
    for (int r = 0; r < 32; ++r) acc[r] = 0.f;

    #pragma unroll 2
    for (int k = 0; k < HID; ++k) {
        const float wv = Wout[(size_t)k * VOC + vc];   // coalesced vector load
        const float* hr = hmT + k * NBATCH + r0;       // uniform -> s_load
        #pragma unroll
        for (int r = 0; r < 32; ++r) acc[r] = fmaf(hr[r], wv, acc[r]);
    }
    const float bv = bout[vc];
    if (v < VOC) {
        for (int r = 0; r < 32; ++r)
            out[(size_t)(r0 + r) * VOC + v] = acc[r] + bv;
    }
}

extern "C" void kernel_launch(void* const* d_in, const int* in_sizes, int n_in,
                              void* d_out, int out_size, void* d_ws, size_t ws_size,
                              hipStream_t stream) {
    const int*   seq  = (const int*)d_in[0];     // (T,N) int32
    const float* msk  = (const float*)d_in[1];   // (T,N)
    const float* topo = (const float*)d_in[2];   // (T,N,T)
    const float* W    = (const float*)d_in[3];   // (H,4H)
    const float* U    = (const float*)d_in[4];   // (H,4H)
    const float* b    = (const float*)d_in[5];   // (4H)
    const float* ET   = (const float*)d_in[6];   // (V,H)
    const float* Wout = (const float*)d_in[7];   // (H,V)
    const float* bout = (const float*)d_in[8];   // (V)
    float* out = (float*)d_out;

    float* XW  = (float*)d_ws;                                   // 102.4 MB
    float* hmT = (float*)((char*)d_ws + (size_t)VOC * G4 * sizeof(float)); // +128 KB

    kxw<<<(VOC + 127) / 128, 1024, 0, stream>>>(ET, W, b, XW);
    k2_recur<<<NBATCH, 1024, 0, stream>>>(topo, msk, U, seq, XW, hmT);
    k3_out<<<dim3(98, 8), 512, 0, stream>>>(hmT, Wout, bout, out);
}